// Round 1
// baseline (51.130 us; speedup 1.0000x reference)
//
#include <hip/hip_runtime.h>

// LBP forward: out[n,f,h,w] = sum_p 2^p * sigmoid((nb - ctr)/0.1)
//   c  = projection_map[f,p]; ky,kx = kernels[f,p,:] in {0,1,2}
//   nb  = xpad[n,c,h+ky,w+kx]  (zero pad of 1)
//   ctr = x[n,c,h,w]
// N=32 D=64 H=56 W=56 F=128 P=4

#define NN 32
#define DD 64
#define HH 56
#define WW 56
#define FF 128
#define PP 4

__global__ __launch_bounds__(448) void lbp_kernel(
    const float* __restrict__ x,    // (N,D,H,W)
    const int*   __restrict__ kern, // (F,P,2)
    const int*   __restrict__ proj, // (F,P)
    float*       __restrict__ out)  // (N,F,H,W)
{
    const int pix = blockIdx.x * 448 + threadIdx.x;  // 0..3135 (=H*W exactly)
    const int h = pix / WW;
    const int w = pix - h * WW;
    const int nf = blockIdx.y;            // n*F + f
    const int f  = nf & (FF - 1);
    const int n  = nf >> 7;

    const float* xn = x + (size_t)n * (DD * HH * WW);

    float acc = 0.f;
    float wt  = 1.f;
#pragma unroll
    for (int p = 0; p < PP; ++p) {
        // uniform per block (f from blockIdx.y) -> scalarized loads
        const int c  = proj[f * PP + p];
        const int ky = kern[(f * PP + p) * 2 + 0];
        const int kx = kern[(f * PP + p) * 2 + 1];

        const float* xc = xn + c * (HH * WW);
        const float ctr = xc[h * WW + w];

        const int y  = h + ky - 1;
        const int xw = w + kx - 1;
        float nb = 0.f;
        if ((unsigned)y < (unsigned)HH && (unsigned)xw < (unsigned)WW)
            nb = xc[y * WW + xw];

        // sigmoid((nb-ctr)/0.1) = 1/(1+exp2((nb-ctr) * -10*log2(e)))
        const float z = (nb - ctr) * -14.4269504089f;
        const float e = __builtin_amdgcn_exp2f(z);
        acc = fmaf(wt, __builtin_amdgcn_rcpf(1.f + e), acc);
        wt *= 2.f;
    }

    out[(size_t)nf * (HH * WW) + pix] = acc;
}

extern "C" void kernel_launch(void* const* d_in, const int* in_sizes, int n_in,
                              void* d_out, int out_size, void* d_ws, size_t ws_size,
                              hipStream_t stream) {
    const float* x    = (const float*)d_in[0];
    const int*   kern = (const int*)d_in[1];
    const int*   proj = (const int*)d_in[2];
    float*       out  = (float*)d_out;

    dim3 grid(7, NN * FF);   // 7*448 = 3136 = H*W pixels per (n,f) plane
    dim3 block(448);
    lbp_kernel<<<grid, block, 0, stream>>>(x, kern, proj, out);
}

// Round 3
// 38.065 us; speedup vs baseline: 1.3432x; 1.3432x over previous
//
#include <hip/hip_runtime.h>

// LBP forward: out[n,f,h,w] = sum_p 2^p * sigmoid((nb - ctr)/0.1)
//   c  = projection_map[f,p]; ky,kx = kernels[f,p,:] in {0,1,2}
//   nb  = xpad[n,c,h+ky-1,w+kx-1]  (zero pad of 1), ctr = x[n,c,h,w]
// N=32 D=64 H=56 W=56 F=128 P=4
//
// Strategy: block = (n, 2-row strip). Stage all 64 channels of the padded
// strip (64 x 4 rows x 58 cols fp32 = 59.4 KB) in LDS + a 4 KB fused offset
// table; loop over all 128 f. Inner loop: 2 ds_read + exp2 + rcp + fma per p.

#define NN 32
#define DD 64
#define HH 56
#define WW 56
#define FF 128
#define PP 4

#define ROWS 2          // output rows per block
#define TR   (ROWS + 2) // tile rows incl. halo
#define TC   (WW + 2)   // 58 padded cols
#define CHS  (TR * TC)  // 232 floats per channel
#define TILE_FLOATS (DD * CHS)  // 14848 floats = 59392 B
#define NTHREADS 448

__global__ __launch_bounds__(NTHREADS) void lbp_kernel(
    const float* __restrict__ x,    // (N,D,H,W)
    const int*   __restrict__ kern, // (F,P,2)
    const int*   __restrict__ proj, // (F,P)
    float*       __restrict__ out)  // (N,F,H,W)
{
    __shared__ float tile[TILE_FLOATS];
    __shared__ int2  tab[FF * PP];   // {c*CHS, c*CHS + (ky-1)*TC + (kx-1)}

    const int tid = threadIdx.x;
    const int n   = blockIdx.y;
    const int h0  = blockIdx.x * ROWS;

    // ---- zero the tile (covers halo/padding) ----
    for (int i = tid; i < TILE_FLOATS; i += NTHREADS)
        tile[i] = 0.f;

    // ---- fused offset tables (FF*PP=512 > NTHREADS=448 -> stride loop!) ----
    for (int i = tid; i < FF * PP; i += NTHREADS) {
        const int c  = proj[i];
        const int ky = kern[2 * i + 0];
        const int kx = kern[2 * i + 1];
        const int cb = c * CHS;
        tab[i] = make_int2(cb, cb + (ky - 1) * TC + (kx - 1));
    }
    __syncthreads();   // zeros + table visible before body writes

    // ---- stage body rows: 64 ch x 4 rows x 14 float4 ----
    const float* xn = x + (size_t)n * (DD * HH * WW);
    for (int item = tid; item < DD * TR * (WW / 4); item += NTHREADS) {
        const int ch  = item / (TR * (WW / 4));
        const int rem = item - ch * (TR * (WW / 4));
        const int tr  = rem / (WW / 4);
        const int v   = rem - tr * (WW / 4);
        const int h   = h0 + tr - 1;
        if ((unsigned)h < (unsigned)HH) {
            const float4 val = *(const float4*)(xn + ch * (HH * WW) + h * WW + v * 4);
            const int base = ch * CHS + tr * TC + 1 + v * 4;
            tile[base + 0] = val.x;
            tile[base + 1] = val.y;
            tile[base + 2] = val.z;
            tile[base + 3] = val.w;
        }
    }
    __syncthreads();

    // ---- compute: 4 concurrent f, 112 pixels each ----
    const int fq  = tid / (ROWS * WW);        // 0..3
    const int pix = tid - fq * (ROWS * WW);   // 0..111
    const int r   = pix / WW;
    const int w   = pix - r * WW;
    const int pp  = (r + 1) * TC + (w + 1);   // padded-tile pixel offset

    float* op = out + ((size_t)n * FF + fq) * (HH * WW) + (h0 + r) * WW + w;

    for (int f = fq; f < FF; f += 4) {
        float acc = 0.f, wt = 1.f;
#pragma unroll
        for (int p = 0; p < PP; ++p) {
            const int2 t = tab[f * PP + p];
            const float ctr = tile[t.x + pp];
            const float nb  = tile[t.y + pp];
            const float z   = (nb - ctr) * -14.4269504089f;
            const float e   = __builtin_amdgcn_exp2f(z);
            acc = fmaf(wt, __builtin_amdgcn_rcpf(1.f + e), acc);
            wt *= 2.f;
        }
        *op = acc;
        op += 4 * (HH * WW);
    }
}

extern "C" void kernel_launch(void* const* d_in, const int* in_sizes, int n_in,
                              void* d_out, int out_size, void* d_ws, size_t ws_size,
                              hipStream_t stream) {
    const float* x    = (const float*)d_in[0];
    const int*   kern = (const int*)d_in[1];
    const int*   proj = (const int*)d_in[2];
    float*       out  = (float*)d_out;

    dim3 grid(HH / ROWS, NN);   // 28 x 32 = 896 blocks
    dim3 block(NTHREADS);
    lbp_kernel<<<grid, block, 0, stream>>>(x, kern, proj, out);
}

// Round 4
// 33.493 us; speedup vs baseline: 1.5266x; 1.1365x over previous
//
#include <hip/hip_runtime.h>

// LBP forward: out[n,f,h,w] = sum_p 2^p * sigmoid((nb - ctr)/0.1)
//   c  = projection_map[f,p]; ky,kx = kernels[f,p,:] in {0,1,2}
//   nb  = xpad[n,c,h+ky-1,w+kx-1]  (zero pad of 1), ctr = x[n,c,h,w]
// N=32 D=64 H=56 W=56 F=128 P=4
//
// Block = (n, 2-row strip). Stage all 64 channels of the padded strip in LDS
// ([64ch][4rows][64cols], interior at col 4, 16B-aligned -> b128 staging).
// Compute: thread = (f-group, column), owns BOTH output rows -> ctr/nb pairs
// fuse to ds_read2_b32 (offset diff 64), conflict-free stride-1 banking.
// Offset table packed as int[F][8] -> 2x ds_read_b128 per f.

#define NN 32
#define DD 64
#define HH 56
#define WW 56
#define FF 128
#define PP 4

#define ROWS 2          // output rows per block
#define TR   (ROWS + 2) // tile rows incl. halo
#define TC   64         // padded cols (interior at 4..59, pads at 3 and 60)
#define COL0 4
#define CHS  (TR * TC)  // 256 floats per channel
#define TILE_FLOATS (DD * CHS)  // 16384 floats = 64 KB
#define NTHREADS 448

__global__ __launch_bounds__(NTHREADS) void lbp_kernel(
    const float* __restrict__ x,    // (N,D,H,W)
    const int*   __restrict__ kern, // (F,P,2)
    const int*   __restrict__ proj, // (F,P)
    float*       __restrict__ out)  // (N,F,H,W)
{
    __shared__ float tile[TILE_FLOATS];
    __shared__ int   tab[FF * 8];   // per f: {x0,y0,x1,y1,x2,y2,x3,y3}

    const int tid = threadIdx.x;
    const int n   = blockIdx.y;
    const int h0  = blockIdx.x * ROWS;

    // ---- fused offset table (512 entries, stride loop) ----
    for (int i = tid; i < FF * PP; i += NTHREADS) {
        const int c  = proj[i];
        const int ky = kern[2 * i + 0];
        const int kx = kern[2 * i + 1];
        const int cb = c * CHS;
        tab[2 * i + 0] = cb;                               // ctr base
        tab[2 * i + 1] = cb + (ky - 1) * TC + (kx - 1);    // nb base
    }

    // ---- zero the kx-pad columns (3 and 60), all ch x rows ----
    for (int i = tid; i < DD * TR * 2; i += NTHREADS) {
        const int ch   = i >> 3;
        const int r    = (i >> 1) & 3;
        const int side = i & 1;
        tile[ch * CHS + r * TC + 3 + side * 57] = 0.f;
    }

    // ---- stage body: 64 ch x 4 rows x 14 float4 (halo rows -> zeros) ----
    const float* xn = x + (size_t)n * (DD * HH * WW);
    for (int item = tid; item < DD * TR * (WW / 4); item += NTHREADS) {
        const int ch  = item / (TR * (WW / 4));
        const int rem = item - ch * (TR * (WW / 4));
        const int tr  = rem / (WW / 4);
        const int v   = rem - tr * (WW / 4);
        const int h   = h0 + tr - 1;
        float4 val = make_float4(0.f, 0.f, 0.f, 0.f);
        if ((unsigned)h < (unsigned)HH)
            val = *(const float4*)(xn + ch * (HH * WW) + h * WW + v * 4);
        *(float4*)(tile + ch * CHS + tr * TC + COL0 + v * 4) = val;  // 16B aligned
    }
    __syncthreads();

    // ---- compute: 8 concurrent f, thread = column, both rows ----
    const int fq = tid / WW;        // 0..7
    const int w  = tid - fq * WW;   // 0..55
    const int pp0 = 1 * TC + COL0 + w;  // tile row 1 = output row h0

    float* op = out + ((size_t)n * FF + fq) * (HH * WW) + (size_t)h0 * WW + w;

    for (int f = fq; f < FF; f += 8) {
        const int4 A = ((const int4*)tab)[2 * f + 0];  // x0,y0,x1,y1
        const int4 B = ((const int4*)tab)[2 * f + 1];  // x2,y2,x3,y3
        float acc0 = 0.f, acc1 = 0.f;
        float wt = 1.f;
        const int cx[4] = {A.x, A.z, B.x, B.z};
        const int nx[4] = {A.y, A.w, B.y, B.w};
#pragma unroll
        for (int p = 0; p < PP; ++p) {
            const float c0 = tile[cx[p] + pp0];
            const float c1 = tile[cx[p] + pp0 + TC];   // fuses -> ds_read2_b32
            const float n0 = tile[nx[p] + pp0];
            const float n1 = tile[nx[p] + pp0 + TC];
            const float z0 = (n0 - c0) * -14.4269504089f;
            const float z1 = (n1 - c1) * -14.4269504089f;
            const float e0 = __builtin_amdgcn_exp2f(z0);
            const float e1 = __builtin_amdgcn_exp2f(z1);
            acc0 = fmaf(wt, __builtin_amdgcn_rcpf(1.f + e0), acc0);
            acc1 = fmaf(wt, __builtin_amdgcn_rcpf(1.f + e1), acc1);
            wt *= 2.f;
        }
        op[0]  = acc0;
        op[WW] = acc1;
        op += 8 * (HH * WW);
    }
}

extern "C" void kernel_launch(void* const* d_in, const int* in_sizes, int n_in,
                              void* d_out, int out_size, void* d_ws, size_t ws_size,
                              hipStream_t stream) {
    const float* x    = (const float*)d_in[0];
    const int*   kern = (const int*)d_in[1];
    const int*   proj = (const int*)d_in[2];
    float*       out  = (float*)d_out;

    dim3 grid(HH / ROWS, NN);   // 28 x 32 = 896 blocks
    dim3 block(NTHREADS);
    lbp_kernel<<<grid, block, 0, stream>>>(x, kern, proj, out);
}

// Round 5
// 32.946 us; speedup vs baseline: 1.5519x; 1.0166x over previous
//
#include <hip/hip_runtime.h>

// LBP forward: out[n,f,h,w] = sum_p 2^p * sigmoid((nb - ctr)/0.1)
//   c  = projection_map[f,p]; ky,kx = kernels[f,p,:] in {0,1,2}
//   nb  = xpad[n,c,h+ky-1,w+kx-1]  (zero pad of 1), ctr = x[n,c,h,w]
// N=32 D=64 H=56 W=56 F=128 P=4
//
// Block = (n, 2-row strip), 896 threads (14 waves). Stage all 64 channels of
// the padded strip in LDS ([64ch][4rows][64cols], interior at col 4, 16B
// aligned -> b128 staging). LDS 69.6KB -> 2 blocks/CU = 28 waves/CU (87%
// occupancy; the round-4 448-thread version was latency-bound at 14/CU).
// Compute: thread = (f-group 0..15, column), owns BOTH output rows -> ctr/nb
// pairs fuse to ds_read2_b32 (offset diff 64), stride-1 banking. Offset table
// packed as int[F][8] -> 2x ds_read_b128 per f, prefetched one f ahead.

#define NN 32
#define DD 64
#define HH 56
#define WW 56
#define FF 128
#define PP 4

#define ROWS 2          // output rows per block
#define TR   (ROWS + 2) // tile rows incl. halo
#define TC   64         // padded cols (interior at 4..59, pads at 3 and 60)
#define COL0 4
#define CHS  (TR * TC)  // 256 floats per channel
#define TILE_FLOATS (DD * CHS)  // 16384 floats = 64 KB
#define NTHREADS 896
#define FQN 16          // concurrent f groups
#define FITER (FF / FQN) // 8 f-iters per thread

__global__ __launch_bounds__(NTHREADS, 7) void lbp_kernel(
    const float* __restrict__ x,    // (N,D,H,W)
    const int*   __restrict__ kern, // (F,P,2)
    const int*   __restrict__ proj, // (F,P)
    float*       __restrict__ out)  // (N,F,H,W)
{
    __shared__ float tile[TILE_FLOATS];
    __shared__ int   tab[FF * 8];   // per f: {x0,y0,x1,y1,x2,y2,x3,y3}

    const int tid = threadIdx.x;
    const int n   = blockIdx.y;
    const int h0  = blockIdx.x * ROWS;

    // ---- fused offset table (512 entries) ----
    if (tid < FF * PP) {
        const int c  = proj[tid];
        const int ky = kern[2 * tid + 0];
        const int kx = kern[2 * tid + 1];
        const int cb = c * CHS;
        tab[2 * tid + 0] = cb;                               // ctr base
        tab[2 * tid + 1] = cb + (ky - 1) * TC + (kx - 1);    // nb base
    }

    // ---- zero the kx-pad columns (3 and 60), all ch x rows ----
    if (tid < DD * TR * 2) {
        const int ch   = tid >> 3;
        const int r    = (tid >> 1) & 3;
        const int side = tid & 1;
        tile[ch * CHS + r * TC + 3 + side * 57] = 0.f;
    }

    // ---- stage body: 64 ch x 4 rows x 14 float4 = 3584 items, 4/thread ----
    const float* xn = x + (size_t)n * (DD * HH * WW);
#pragma unroll
    for (int it = 0; it < 4; ++it) {
        const int item = tid + it * NTHREADS;
        const int ch  = item / (TR * (WW / 4));
        const int rem = item - ch * (TR * (WW / 4));
        const int tr  = rem / (WW / 4);
        const int v   = rem - tr * (WW / 4);
        const int h   = h0 + tr - 1;
        float4 val = make_float4(0.f, 0.f, 0.f, 0.f);
        if ((unsigned)h < (unsigned)HH)
            val = *(const float4*)(xn + ch * (HH * WW) + h * WW + v * 4);
        *(float4*)(tile + ch * CHS + tr * TC + COL0 + v * 4) = val;  // 16B aligned
    }
    __syncthreads();

    // ---- compute: 16 concurrent f, thread = column, both rows ----
    const int fq = tid / WW;        // 0..15
    const int w  = tid - fq * WW;   // 0..55
    const int pp0 = 1 * TC + COL0 + w;  // tile row 1 = output row h0

    float* op = out + ((size_t)n * FF + fq) * (HH * WW) + (size_t)h0 * WW + w;
    const int4* tab4 = (const int4*)tab;

    int f = fq;
    int4 A = tab4[2 * f + 0];       // x0,y0,x1,y1
    int4 B = tab4[2 * f + 1];       // x2,y2,x3,y3

#pragma unroll
    for (int k = 0; k < FITER; ++k) {
        int4 An, Bn;
        if (k < FITER - 1) {        // prefetch next f's table
            An = tab4[2 * (f + FQN) + 0];
            Bn = tab4[2 * (f + FQN) + 1];
        }
        const int cx[4] = {A.x, A.z, B.x, B.z};
        const int nx[4] = {A.y, A.w, B.y, B.w};
        float acc0 = 0.f, acc1 = 0.f;
        float wt = 1.f;
#pragma unroll
        for (int p = 0; p < PP; ++p) {
            const float c0 = tile[cx[p] + pp0];
            const float c1 = tile[cx[p] + pp0 + TC];   // fuses -> ds_read2_b32
            const float n0 = tile[nx[p] + pp0];
            const float n1 = tile[nx[p] + pp0 + TC];
            const float z0 = (n0 - c0) * -14.4269504089f;
            const float z1 = (n1 - c1) * -14.4269504089f;
            const float e0 = __builtin_amdgcn_exp2f(z0);
            const float e1 = __builtin_amdgcn_exp2f(z1);
            acc0 = fmaf(wt, __builtin_amdgcn_rcpf(1.f + e0), acc0);
            acc1 = fmaf(wt, __builtin_amdgcn_rcpf(1.f + e1), acc1);
            wt *= 2.f;
        }
        op[0]  = acc0;
        op[WW] = acc1;
        op += FQN * (HH * WW);
        f  += FQN;
        A = An; B = Bn;
    }
}

extern "C" void kernel_launch(void* const* d_in, const int* in_sizes, int n_in,
                              void* d_out, int out_size, void* d_ws, size_t ws_size,
                              hipStream_t stream) {
    const float* x    = (const float*)d_in[0];
    const int*   kern = (const int*)d_in[1];
    const int*   proj = (const int*)d_in[2];
    float*       out  = (float*)d_out;

    dim3 grid(HH / ROWS, NN);   // 28 x 32 = 896 blocks
    dim3 block(NTHREADS);
    lbp_kernel<<<grid, block, 0, stream>>>(x, kern, proj, out);
}

// Round 6
// 32.105 us; speedup vs baseline: 1.5926x; 1.0262x over previous
//
#include <hip/hip_runtime.h>

// LBP forward: out[n,f,h,w] = sum_p 2^p * sigmoid((nb - ctr)/0.1)
//   c  = projection_map[f,p]; ky,kx = kernels[f,p,:] in {0,1,2}
//   nb  = xpad[n,c,h+ky-1,w+kx-1]  (zero pad of 1), ctr = x[n,c,h,w]
//   NOTE: ctr and nb are the SAME channel c -> per (f,p) it's a 3x3 stencil.
// N=32 D=64 H=56 W=56 F=128 P=4
//
// Block = (n, 2-row strip), 1024 threads = 16 waves, 2 blocks/CU (64 KB LDS,
// <=64 VGPR) = 32 waves/CU. Wave = one f-group: f is wave-uniform, so the
// (proj, kern) tables are SCALAR loads (s_load_dwordx4/x8) and all per-f
// offsets live in SGPRs -- no LDS table, one less LDS round-trip per f.
// Lanes = columns (56 active of 64); each lane owns both output rows, so
// ctr/nb row-pairs fuse to ds_read2_b32 (offset diff 64), pure stride-1.

#define NN 32
#define DD 64
#define HH 56
#define WW 56
#define FF 128
#define PP 4

#define ROWS 2          // output rows per block
#define TR   (ROWS + 2) // tile rows incl. halo
#define TC   64         // padded cols (interior at 4..59, pads at 3 and 60)
#define COL0 4
#define CHS  (TR * TC)  // 256 floats per channel
#define TILE_FLOATS (DD * CHS)  // 16384 floats = 64 KB
#define NTHREADS 1024
#define NWAVES 16            // concurrent f groups (one per wave)
#define FITER (FF / NWAVES)  // 8 f per wave

__global__ __launch_bounds__(NTHREADS, 8) void lbp_kernel(
    const float* __restrict__ x,    // (N,D,H,W)
    const int*   __restrict__ kern, // (F,P,2)
    const int*   __restrict__ proj, // (F,P)
    float*       __restrict__ out)  // (N,F,H,W)
{
    __shared__ float tile[TILE_FLOATS];

    const int tid = threadIdx.x;
    const int n   = blockIdx.y;
    const int h0  = blockIdx.x * ROWS;

    // ---- zero the kx-pad columns (3 and 60), all ch x rows ----
    if (tid < DD * TR * 2) {
        const int ch   = tid >> 3;
        const int r    = (tid >> 1) & 3;
        const int side = tid & 1;
        tile[ch * CHS + r * TC + 3 + side * 57] = 0.f;
    }

    // ---- stage body: 64 ch x 4 rows x 14 float4 = 3584 items ----
    const float* xn = x + (size_t)n * (DD * HH * WW);
#pragma unroll
    for (int it = 0; it < 4; ++it) {
        const int item = tid + it * NTHREADS;
        if (item < DD * TR * (WW / 4)) {
            const int ch  = item / (TR * (WW / 4));
            const int rem = item - ch * (TR * (WW / 4));
            const int tr  = rem / (WW / 4);
            const int v   = rem - tr * (WW / 4);
            const int h   = h0 + tr - 1;
            float4 val = make_float4(0.f, 0.f, 0.f, 0.f);
            if ((unsigned)h < (unsigned)HH)
                val = *(const float4*)(xn + ch * (HH * WW) + h * WW + v * 4);
            *(float4*)(tile + ch * CHS + tr * TC + COL0 + v * 4) = val;  // 16B aligned
        }
    }
    __syncthreads();

    // ---- compute: wave = f-group, lane = column, both rows ----
    const int wid  = __builtin_amdgcn_readfirstlane(tid >> 6);  // 0..15, SGPR
    const int lane = tid & 63;
    const int w    = lane < WW ? lane : WW - 1;   // clamp idle lanes (reads broadcast)
    const bool act = lane < WW;
    const int pp0  = 1 * TC + COL0 + w;           // tile row 1 = output row h0

    for (int k = 0; k < FITER; ++k) {
        const int f = wid + k * NWAVES;           // wave-uniform

        // scalar table loads: proj row (16B) + kern row (32B)
        const int4 pj = *(const int4*)(proj + f * PP);       // c0..c3
        const int4 ka = *(const int4*)(kern + f * PP * 2);   // ky0,kx0,ky1,kx1
        const int4 kb = *(const int4*)(kern + f * PP * 2 + 4); // ky2,kx2,ky3,kx3

        const int c0 = pj.x * CHS, c1 = pj.y * CHS, c2 = pj.z * CHS, c3 = pj.w * CHS;
        const int coff[4] = {c0, c1, c2, c3};
        const int noff[4] = {c0 + (ka.x - 1) * TC + (ka.y - 1),
                             c1 + (ka.z - 1) * TC + (ka.w - 1),
                             c2 + (kb.x - 1) * TC + (kb.y - 1),
                             c3 + (kb.z - 1) * TC + (kb.w - 1)};

        float acc0 = 0.f, acc1 = 0.f;
        float wt = 1.f;
#pragma unroll
        for (int p = 0; p < PP; ++p) {
            const float x0 = tile[coff[p] + pp0];
            const float x1 = tile[coff[p] + pp0 + TC];   // fuses -> ds_read2_b32
            const float y0 = tile[noff[p] + pp0];
            const float y1 = tile[noff[p] + pp0 + TC];
            const float z0 = (y0 - x0) * -14.4269504089f;
            const float z1 = (y1 - x1) * -14.4269504089f;
            const float e0 = __builtin_amdgcn_exp2f(z0);
            const float e1 = __builtin_amdgcn_exp2f(z1);
            acc0 = fmaf(wt, __builtin_amdgcn_rcpf(1.f + e0), acc0);
            acc1 = fmaf(wt, __builtin_amdgcn_rcpf(1.f + e1), acc1);
            wt *= 2.f;
        }
        if (act) {
            float* op = out + ((size_t)n * FF + f) * (HH * WW) + (size_t)h0 * WW + w;
            op[0]  = acc0;
            op[WW] = acc1;
        }
    }
}

extern "C" void kernel_launch(void* const* d_in, const int* in_sizes, int n_in,
                              void* d_out, int out_size, void* d_ws, size_t ws_size,
                              hipStream_t stream) {
    const float* x    = (const float*)d_in[0];
    const int*   kern = (const int*)d_in[1];
    const int*   proj = (const int*)d_in[2];
    float*       out  = (float*)d_out;

    dim3 grid(HH / ROWS, NN);   // 28 x 32 = 896 blocks
    dim3 block(NTHREADS);
    lbp_kernel<<<grid, block, 0, stream>>>(x, kern, proj, out);
}